// Round 10
// baseline (231.437 us; speedup 1.0000x reference)
//
#include <hip/hip_runtime.h>

// x: (64, 8192, 256) float32, cumsum along dim 1.
#define BATCH 64
#define LEN   8192
#define DIM   256
#define D4    (DIM / 4)        // 64 float4 per row
#define Q     8                // channel slices per batch (128 B/row slice = 1 cache line)
#define SF4   (D4 / Q)         // 8 float4 per slice
#define NTHR  512
#define R     4                // rows per thread per tile
#define GROUPS (NTHR / SF4)    // 64 row-groups per tile
#define TILE  (GROUPS * R)     // 256 rows per tile
#define NT    (LEN / TILE)     // 32 tiles, serial per block (carry in regs)
#define NWAVES (NTHR / 64)     // 8

__device__ __forceinline__ void f4_add(float4& a, const float4& v) {
    a.x += v.x; a.y += v.y; a.z += v.z; a.w += v.w;
}

// One block owns the full 8192-row chain of a (batch, 32-channel slice).
// Serial over 32 tiles of 256 rows; carry in registers; x read once, out once.
// KEY (round 10): the per-tile __syncthreads is replaced by an LDS
// monotonic-counter barrier. s_barrier forces the compiler to emit
// s_waitcnt vmcnt(0) (full VMEM drain) every tile; the LDS barrier only
// touches lgkmcnt, so prefetch loads and deferred stores stay in flight
// across tile boundaries — copy-like continuous memory traffic.
__global__ __launch_bounds__(NTHR, 2) void chained_scan_kernel(
    const float* __restrict__ x, float* __restrict__ out)
{
    __shared__ float4 wtot[2][NWAVES][SF4];   // 2 KiB, parity double-buffered
    __shared__ int barcnt;                    // monotonic arrival counter

    const int q    = blockIdx.x;         // channel slice
    const int b    = blockIdx.y;         // batch
    const int t    = threadIdx.x;        // 0..511
    const int f    = t & (SF4 - 1);      // f4 within slice (0..7)
    const int g    = t >> 3;             // group within tile (0..63), 4 rows each
    const int lane = t & 63;
    const int w    = t >> 6;             // wave 0..7
    const int lg   = lane >> 3;          // local group within wave (0..7)

    if (t == 0) barcnt = 0;
    __syncthreads();                     // once, at entry

    const size_t chain = (size_t)b * LEN * D4 + (size_t)q * SF4 + f;
    const float4* xp = reinterpret_cast<const float4*>(x) + chain;
    float4*       op = reinterpret_cast<float4*>(out) + chain;
    const size_t r0 = (size_t)(g * R) * D4;  // thread's first row offset in a tile

    float4 carry = make_float4(0.f, 0.f, 0.f, 0.f);

    // Prefetch tile 0.
    float4 a[R];
#pragma unroll
    for (int r = 0; r < R; ++r) a[r] = xp[r0 + (size_t)r * D4];

    float4 held[R];                      // deferred output rows of previous tile
    size_t held_ob = 0;

    for (int tile = 0; tile < NT; ++tile) {
        // 1) Issue next tile's loads.
        const int nxt = (tile + 1 < NT) ? tile + 1 : tile;
        const size_t nb = (size_t)nxt * TILE * D4 + r0;
        float4 nx[R];
#pragma unroll
        for (int r = 0; r < R; ++r) nx[r] = xp[nb + (size_t)r * D4];

        // 2) Flush previous tile's outputs — overlaps with loads, and with
        //    the vmcnt drain gone these ride across the tile boundary.
        if (tile > 0) {
#pragma unroll
            for (int r = 0; r < R; ++r)
                op[held_ob + (size_t)r * D4] = held[r];
        }

        // 3) Tile scan. 4-row group sum:
        float4 ls = a[0];
        f4_add(ls, a[1]); f4_add(ls, a[2]); f4_add(ls, a[3]);

        // Wave-inclusive scan over the 8 local groups (same-f lanes, stride 8).
        float4 incl = ls;
#pragma unroll
        for (int d = 1; d < 8; d <<= 1) {
            float4 o;
            o.x = __shfl_up(incl.x, d * SF4, 64);
            o.y = __shfl_up(incl.y, d * SF4, 64);
            o.z = __shfl_up(incl.z, d * SF4, 64);
            o.w = __shfl_up(incl.w, d * SF4, 64);
            if (lg >= d) f4_add(incl, o);
        }

        // Publish per-wave totals (last local group holds them), parity-buffered.
        const int par = tile & 1;
        if (lane >= 56) wtot[par][w][f] = incl;

        // LDS-only barrier: order the wtot write, signal arrival, spin.
        asm volatile("s_waitcnt lgkmcnt(0)" ::: "memory");
        if (lane == 0)
            __hip_atomic_fetch_add(&barcnt, 1, __ATOMIC_RELAXED,
                                   __HIP_MEMORY_SCOPE_WORKGROUP);
        const int target = (tile + 1) * NWAVES;
        while (__hip_atomic_load(&barcnt, __ATOMIC_RELAXED,
                                 __HIP_MEMORY_SCOPE_WORKGROUP) < target) { }

        // Cross-wave exclusive prefix + tile total (8 broadcast reads).
        float4 cross = make_float4(0.f, 0.f, 0.f, 0.f);
        float4 tot   = make_float4(0.f, 0.f, 0.f, 0.f);
#pragma unroll
        for (int ww = 0; ww < NWAVES; ++ww) {
            float4 s = wtot[par][ww][f];
            if (ww < w) f4_add(cross, s);
            f4_add(tot, s);
        }

        // acc = carry + exclusive-prefix-of-this-group = carry + cross + incl - ls
        float4 acc = carry;
        f4_add(acc, cross);
        f4_add(acc, incl);
        acc.x -= ls.x; acc.y -= ls.y; acc.z -= ls.z; acc.w -= ls.w;

        // 4) Produce this tile's outputs into held registers (store next iter).
#pragma unroll
        for (int r = 0; r < R; ++r) {
            f4_add(acc, a[r]);
            held[r] = acc;
        }
        held_ob = (size_t)tile * TILE * D4 + r0;

        f4_add(carry, tot);
#pragma unroll
        for (int r = 0; r < R; ++r) a[r] = nx[r];
    }

    // Flush the final tile's outputs.
#pragma unroll
    for (int r = 0; r < R; ++r)
        op[held_ob + (size_t)r * D4] = held[r];
}

extern "C" void kernel_launch(void* const* d_in, const int* in_sizes, int n_in,
                              void* d_out, int out_size, void* d_ws, size_t ws_size,
                              hipStream_t stream) {
    const float* x = (const float*)d_in[0];
    float* out = (float*)d_out;
    chained_scan_kernel<<<dim3(Q, BATCH), NTHR, 0, stream>>>(x, out);
}

// Round 11
// 221.711 us; speedup vs baseline: 1.0439x; 1.0439x over previous
//
#include <hip/hip_runtime.h>

// x: (64, 8192, 256) float32, cumsum along dim 1.
#define BATCH 64
#define LEN   8192
#define DIM   256
#define D4    (DIM / 4)        // 64 float4 per row
#define Q     4                // channel slices per batch: 256 B per slice-row
#define SF4   (D4 / Q)         // 16 float4 per slice
#define NTHR  512
#define R     8                // rows per thread per tile
#define GROUPS (NTHR / SF4)    // 32 row-groups per tile
#define TILE  (GROUPS * R)     // 256 rows per tile
#define NT    (LEN / TILE)     // 32 tiles, serial per block (carry in regs)
#define NWAVES (NTHR / 64)     // 8
#define LGW   (64 / SF4)       // 4 local groups per wave

__device__ __forceinline__ void f4_add(float4& a, const float4& v) {
    a.x += v.x; a.y += v.y; a.z += v.z; a.w += v.w;
}

// One block owns the full 8192-row chain of a (batch, 64-channel slice).
// Serial over 32 tiles of 256 rows; carry in registers; x read once, out once.
// ROUND 11: chunk width 128 B -> 256 B (Q=4). Each 16-lane group reads/writes
// a 256 B contiguous run; a wave's load instruction = 4 runs of 256 B.
// Wider sequential runs per requester = fewer DRAM row activations per byte
// and better write-combining on the mixed R/W stream.
__global__ __launch_bounds__(NTHR, 2) void chained_scan_kernel(
    const float* __restrict__ x, float* __restrict__ out)
{
    __shared__ float4 wtot[2][NWAVES][SF4];   // 4 KiB, parity double-buffered

    const int q    = blockIdx.x;         // channel slice
    const int b    = blockIdx.y;         // batch
    const int t    = threadIdx.x;        // 0..511
    const int f    = t & (SF4 - 1);      // f4 within slice (0..15)
    const int g    = t >> 4;             // group within tile (0..31), 8 rows each
    const int lane = t & 63;
    const int w    = t >> 6;             // wave 0..7
    const int lg   = lane >> 4;          // local group within wave (0..3)

    const size_t chain = (size_t)b * LEN * D4 + (size_t)q * SF4 + f;
    const float4* xp = reinterpret_cast<const float4*>(x) + chain;
    float4*       op = reinterpret_cast<float4*>(out) + chain;
    const size_t r0 = (size_t)(g * R) * D4;  // thread's first row offset in a tile

    float4 carry = make_float4(0.f, 0.f, 0.f, 0.f);

    // Prefetch tile 0.
    float4 a[R];
#pragma unroll
    for (int r = 0; r < R; ++r) a[r] = xp[r0 + (size_t)r * D4];

    float4 held[R];                      // deferred output rows of previous tile
    size_t held_ob = 0;

    for (int tile = 0; tile < NT; ++tile) {
        // 1) Issue next tile's loads.
        const int nxt = (tile + 1 < NT) ? tile + 1 : tile;
        const size_t nb = (size_t)nxt * TILE * D4 + r0;
        float4 nx[R];
#pragma unroll
        for (int r = 0; r < R; ++r) nx[r] = xp[nb + (size_t)r * D4];

        // 2) Flush previous tile's outputs (overlaps with the loads above).
        if (tile > 0) {
#pragma unroll
            for (int r = 0; r < R; ++r)
                op[held_ob + (size_t)r * D4] = held[r];
        }

        // 3) 8-row group sum.
        float4 ls = a[0];
#pragma unroll
        for (int r = 1; r < R; ++r) f4_add(ls, a[r]);

        // Wave-inclusive scan over the 4 local groups (same-f lanes, stride 16).
        float4 incl = ls;
#pragma unroll
        for (int d = 1; d < LGW; d <<= 1) {
            float4 o;
            o.x = __shfl_up(incl.x, d * SF4, 64);
            o.y = __shfl_up(incl.y, d * SF4, 64);
            o.z = __shfl_up(incl.z, d * SF4, 64);
            o.w = __shfl_up(incl.w, d * SF4, 64);
            if (lg >= d) f4_add(incl, o);
        }

        // Publish per-wave totals (last local group, lanes 48..63), parity-buffered.
        const int par = tile & 1;
        if (lane >= 48) wtot[par][w][f] = incl;
        __syncthreads();

        // Cross-wave exclusive prefix + tile total (8 broadcast reads).
        float4 cross = make_float4(0.f, 0.f, 0.f, 0.f);
        float4 tot   = make_float4(0.f, 0.f, 0.f, 0.f);
#pragma unroll
        for (int ww = 0; ww < NWAVES; ++ww) {
            float4 s = wtot[par][ww][f];
            if (ww < w) f4_add(cross, s);
            f4_add(tot, s);
        }

        // acc = carry + exclusive-prefix-of-this-group = carry + cross + incl - ls
        float4 acc = carry;
        f4_add(acc, cross);
        f4_add(acc, incl);
        acc.x -= ls.x; acc.y -= ls.y; acc.z -= ls.z; acc.w -= ls.w;

        // 4) Produce this tile's outputs into held registers (store next iter).
#pragma unroll
        for (int r = 0; r < R; ++r) {
            f4_add(acc, a[r]);
            held[r] = acc;
        }
        held_ob = (size_t)tile * TILE * D4 + r0;

        f4_add(carry, tot);
#pragma unroll
        for (int r = 0; r < R; ++r) a[r] = nx[r];
    }

    // Flush the final tile's outputs.
#pragma unroll
    for (int r = 0; r < R; ++r)
        op[held_ob + (size_t)r * D4] = held[r];
}

extern "C" void kernel_launch(void* const* d_in, const int* in_sizes, int n_in,
                              void* d_out, int out_size, void* d_ws, size_t ws_size,
                              hipStream_t stream) {
    const float* x = (const float*)d_in[0];
    float* out = (float*)d_out;
    chained_scan_kernel<<<dim3(Q, BATCH), NTHR, 0, stream>>>(x, out);
}